// Round 7
// baseline (251.420 us; speedup 1.0000x reference)
//
#include <hip/hip_runtime.h>
#include <hip/hip_fp16.h>

#define NNODES 50000
#define NEDGES 800000
#define CIN 64
#define COUT 32
#define NSH 9
#define HDIM 32

#define NT_BLOCKS 6250      // 50000*32/256
#define HIST_BLOCKS 782     // ceil(800000/4/256)

// ---- shared prep body: collapsed W3/b3 + SH-combined layer-1 params
// prm layout: [b1e(32) | A(32) | B(32) | C(32) | D(32) | E(32)]
__device__ __forceinline__ void prep_body(
    int t, const float* __restrict__ W3, const float* __restrict__ b3,
    const float* __restrict__ W1, const float* __restrict__ b1,
    float* __restrict__ W3s, float* __restrict__ b3s, float* __restrict__ prm)
{
    if (t < HDIM * COUT) {
        int k = t >> 5, c = t & 31;
        float s = 0.f;
        #pragma unroll
        for (int q = 0; q < NSH; ++q) s += W3[k * (NSH * COUT) + q * COUT + c];
        W3s[t] = s;
    }
    if (t < COUT) {
        float s = 0.f;
        #pragma unroll
        for (int q = 0; q < NSH; ++q) s += b3[q * COUT + t];
        b3s[t] = s;
    }
    if (t < HDIM) {
        const float c00 = 0.28209479177387814f;
        const float c1  = 0.3454941494713355f;
        const float c1z = 0.4886025119029199f;
        const float c2  = 0.38627420202318958f;
        const float c2z = 0.7725484040463791f;
        const float c20 = 0.31539156525252005f;
        prm[t]       = b1[t] + c00 * W1[0 * HDIM + t];
        prm[32 + t]  = c1  * (W1[3 * HDIM + t] - W1[1 * HDIM + t]);   // x
        prm[64 + t]  = c1z *  W1[2 * HDIM + t];                       // z
        prm[96 + t]  = c2z * (W1[7 * HDIM + t] - W1[5 * HDIM + t]);   // zx
        prm[128 + t] = c2  * (W1[4 * HDIM + t] + W1[8 * HDIM + t]);   // x^2-y^2
        prm[160 + t] = c20 *  W1[6 * HDIM + t];                       // 2z^2-x^2-y^2
    }
}

__global__ void prep_w3(const float* __restrict__ W3, const float* __restrict__ b3,
                        const float* __restrict__ W1, const float* __restrict__ b1,
                        float* __restrict__ W3s, float* __restrict__ b3s,
                        float* __restrict__ prm) {
    prep_body(threadIdx.x, W3, b3, W1, b1, W3s, b3s, prm);
}

// ---- fused: node transform g1(fp16) = feat @ W1[9:,:]  +  edge-row histogram
__global__ __launch_bounds__(256) void nt_hist(
    const float* __restrict__ feat, const float* __restrict__ W1,
    const int* __restrict__ ei, __half* __restrict__ g1h,
    int* __restrict__ cnt, int do_nt)
{
    int b = blockIdx.x;
    if (do_nt && b < NT_BLOCKS) {
        int tid = b * 256 + threadIdx.x;
        int n = tid >> 5, c = tid & 31;
        if (n < NNODES) {
            float acc = 0.f;
            const float* fr = feat + (size_t)n * CIN;
            const float* wp = W1 + NSH * HDIM + c;
            #pragma unroll 8
            for (int k = 0; k < CIN; ++k)
                acc = fmaf(fr[k], wp[k * HDIM], acc);
            g1h[(size_t)n * HDIM + c] = __float2half(acc);
        }
    } else {
        int hb = do_nt ? (b - NT_BLOCKS) : b;
        int e4 = (hb * 256 + threadIdx.x) * 4;
        if (e4 < NEDGES) {
            int4 r = *reinterpret_cast<const int4*>(ei + e4);
            atomicAdd(&cnt[r.x], 1);
            atomicAdd(&cnt[r.y], 1);
            atomicAdd(&cnt[r.z], 1);
            atomicAdd(&cnt[r.w], 1);
        }
    }
}

// ---- fused: block 0 = single-block exclusive scan (proven round-3 code),
//             block 1 = weight prep
__global__ __launch_bounds__(1024) void scan_all(
    const int* __restrict__ cnt, int* __restrict__ off, int* __restrict__ cursor,
    const float* __restrict__ W3, const float* __restrict__ b3,
    const float* __restrict__ W1, const float* __restrict__ b1,
    float* __restrict__ W3s, float* __restrict__ b3s, float* __restrict__ prm)
{
    if (blockIdx.x == 1) {
        prep_body(threadIdx.x, W3, b3, W1, b1, W3s, b3s, prm);
        return;
    }
    __shared__ int lds[1024];
    const int C = (NNODES + 1023) / 1024;  // 49
    int t = threadIdx.x;
    int begin = t * C, end = min(begin + C, NNODES);
    int s = 0;
    for (int i = begin; i < end; ++i) s += cnt[i];
    lds[t] = s;
    __syncthreads();
    for (int d = 1; d < 1024; d <<= 1) {
        int v = (t >= d) ? lds[t - d] : 0;
        __syncthreads();
        lds[t] += v;
        __syncthreads();
    }
    int base = (t == 0) ? 0 : lds[t - 1];
    for (int i = begin; i < end; ++i) {
        off[i] = base;
        cursor[i] = base;
        base += cnt[i];
    }
    if (t == 1023) off[NNODES] = lds[1023];
}

__device__ __forceinline__ float fast_silu(float v) {
    return v * __builtin_amdgcn_rcpf(1.f + __expf(-v));
}

// ---- main edge kernel: g1(fp16) + SH-combined params, fp16 msg output
__global__ __launch_bounds__(256) void edge_compute_g1(
    const __half* __restrict__ g1h, const float* __restrict__ pos,
    const float* __restrict__ prm,
    const float* __restrict__ W2, const float* __restrict__ b2,
    const float* __restrict__ W3s, const float* __restrict__ b3s,
    const int* __restrict__ ei, int* __restrict__ cursor,
    unsigned int* __restrict__ msg)
{
    int e = blockIdx.x * blockDim.x + threadIdx.x;
    if (e >= NEDGES) return;
    int row = ei[e];
    int col = ei[NEDGES + e];

    // claim slot EARLY: atomic latency hides under the MLP below
    int slot = atomicAdd(&cursor[row], 1);
    unsigned int* mp = msg + (size_t)slot * 16;

    float px = pos[3 * row + 0] - pos[3 * col + 0];
    float py = pos[3 * row + 1] - pos[3 * col + 1];
    float pz = pos[3 * row + 2] - pos[3 * col + 2];
    float r2 = px * px + py * py + pz * pz;
    // guarded rsq: self-loops (r2==0) give x=y=z=0 exactly, matching reference
    float rs = (r2 >= 1e-16f) ? __builtin_amdgcn_rsqf(r2) : 0.f;
    float x = px * rs, y = py * rs, z = pz * rs;

    float zx = z * x;
    float xxyy = x * x - y * y;
    float w6 = 2.f * z * z - x * x - y * y;

    const float* b1e = prm;
    const float* A = prm + 32;
    const float* B = prm + 64;
    const float* C = prm + 96;
    const float* D = prm + 128;
    const float* E = prm + 160;

    // load g1[col] (32 fp16 = 64B) and unpack
    float h1[HDIM];
    const uint4* g4 = reinterpret_cast<const uint4*>(g1h + (size_t)col * HDIM);
    #pragma unroll
    for (int q = 0; q < 4; ++q) {
        uint4 u = g4[q];
        const unsigned int uw[4] = {u.x, u.y, u.z, u.w};
        #pragma unroll
        for (int j = 0; j < 4; ++j) {
            float2 f = __half22float2(*reinterpret_cast<const __half2*>(&uw[j]));
            h1[8 * q + 2 * j]     = f.x;
            h1[8 * q + 2 * j + 1] = f.y;
        }
    }
    #pragma unroll
    for (int c = 0; c < HDIM; ++c) {
        float v = h1[c] + b1e[c];
        v = fmaf(x, A[c], v);
        v = fmaf(z, B[c], v);
        v = fmaf(zx, C[c], v);
        v = fmaf(xxyy, D[c], v);
        v = fmaf(w6, E[c], v);
        h1[c] = fast_silu(v);
    }

    float h2[HDIM];
    #pragma unroll
    for (int c = 0; c < HDIM; ++c) h2[c] = b2[c];
    for (int k = 0; k < HDIM; ++k) {
        float v = h1[k];
        #pragma unroll
        for (int c = 0; c < HDIM; ++c) h2[c] = fmaf(v, W2[k * HDIM + c], h2[c]);
    }
    #pragma unroll
    for (int c = 0; c < HDIM; ++c) h2[c] = fast_silu(h2[c]);

    float m[COUT];
    #pragma unroll
    for (int c = 0; c < COUT; ++c) m[c] = b3s[c];
    for (int k = 0; k < HDIM; ++k) {
        float v = h2[k];
        #pragma unroll
        for (int c = 0; c < COUT; ++c) m[c] = fmaf(v, W3s[k * COUT + c], m[c]);
    }

    // pack to fp16 and store 64B
    uint4 pk[4];
    unsigned int* pu = reinterpret_cast<unsigned int*>(pk);
    #pragma unroll
    for (int q = 0; q < 16; ++q) {
        __half2 hh = __floats2half2_rn(m[2 * q], m[2 * q + 1]);
        pu[q] = *reinterpret_cast<unsigned int*>(&hh);
    }
    uint4* mp4 = reinterpret_cast<uint4*>(mp);
    #pragma unroll
    for (int q = 0; q < 4; ++q) mp4[q] = pk[q];
}

// ---- gather: one wave per node; lane=16g+p; 4 slots (256B) per iter
__global__ __launch_bounds__(256) void gather_kernel(
    const unsigned int* __restrict__ msg, const int* __restrict__ off,
    float* __restrict__ out)
{
    int node = blockIdx.x * 4 + (threadIdx.x >> 6);
    if (node >= NNODES) return;
    int lane = threadIdx.x & 63;
    int g = lane >> 4, p = lane & 15;
    int s0 = off[node], s1 = off[node + 1];
    float ax = 0.f, ay = 0.f;
    for (int s = s0 + g; s < s1; s += 4) {
        unsigned int u = msg[(size_t)s * 16 + p];
        __half2 h = *reinterpret_cast<__half2*>(&u);
        ax += __low2float(h);
        ay += __high2float(h);
    }
    ax += __shfl_xor(ax, 16); ay += __shfl_xor(ay, 16);
    ax += __shfl_xor(ax, 32); ay += __shfl_xor(ay, 32);
    if (lane < 16)
        reinterpret_cast<float2*>(out + (size_t)node * COUT)[p] = make_float2(ax, ay);
}

// ---- fallback: direct fp32 atomic scatter (only if ws too small)
__global__ __launch_bounds__(256) void edge_atomic_kernel(
    const float* __restrict__ feat, const float* __restrict__ pos,
    const float* __restrict__ W1, const float* __restrict__ b1,
    const float* __restrict__ W2, const float* __restrict__ b2,
    const float* __restrict__ W3s, const float* __restrict__ b3s,
    const int* __restrict__ ei, float* __restrict__ out)
{
    int e = blockIdx.x * blockDim.x + threadIdx.x;
    if (e >= NEDGES) return;
    int row = ei[e];
    int col = ei[NEDGES + e];

    float px = pos[3 * row + 0] - pos[3 * col + 0];
    float py = pos[3 * row + 1] - pos[3 * col + 1];
    float pz = pos[3 * row + 2] - pos[3 * col + 2];
    float r2 = px * px + py * py + pz * pz;
    float rs = (r2 >= 1e-16f) ? __builtin_amdgcn_rsqf(r2) : 0.f;
    float x = px * rs, y = py * rs, z = pz * rs;

    const float c00 = 0.28209479177387814f;
    const float c1  = 0.3454941494713355f;
    const float c1z = 0.4886025119029199f;
    const float c2  = 0.38627420202318958f;
    const float c2z = 0.7725484040463791f;
    const float c20 = 0.31539156525252005f;

    float sh[NSH];
    float xxyy = x * x - y * y;
    float zx = z * x;
    sh[0] = c00;
    sh[1] = -c1 * x;
    sh[2] = c1z * z;
    sh[3] = c1 * x;
    sh[4] = c2 * xxyy;
    sh[5] = -c2z * zx;
    sh[6] = c20 * (2.f * z * z - x * x - y * y);
    sh[7] = c2z * zx;
    sh[8] = c2 * xxyy;

    float h1[HDIM];
    #pragma unroll
    for (int c = 0; c < HDIM; ++c) h1[c] = b1[c];
    #pragma unroll
    for (int k = 0; k < NSH; ++k) {
        float v = sh[k];
        #pragma unroll
        for (int c = 0; c < HDIM; ++c) h1[c] = fmaf(v, W1[k * HDIM + c], h1[c]);
    }
    const float4* f4 = reinterpret_cast<const float4*>(feat + (size_t)col * CIN);
    for (int kk = 0; kk < CIN / 4; ++kk) {
        float4 f = f4[kk];
        const float* Wp = W1 + (NSH + kk * 4) * HDIM;
        #pragma unroll
        for (int c = 0; c < HDIM; ++c) h1[c] = fmaf(f.x, Wp[c], h1[c]);
        #pragma unroll
        for (int c = 0; c < HDIM; ++c) h1[c] = fmaf(f.y, Wp[HDIM + c], h1[c]);
        #pragma unroll
        for (int c = 0; c < HDIM; ++c) h1[c] = fmaf(f.z, Wp[2 * HDIM + c], h1[c]);
        #pragma unroll
        for (int c = 0; c < HDIM; ++c) h1[c] = fmaf(f.w, Wp[3 * HDIM + c], h1[c]);
    }
    #pragma unroll
    for (int c = 0; c < HDIM; ++c) h1[c] = fast_silu(h1[c]);

    float h2[HDIM];
    #pragma unroll
    for (int c = 0; c < HDIM; ++c) h2[c] = b2[c];
    for (int k = 0; k < HDIM; ++k) {
        float v = h1[k];
        #pragma unroll
        for (int c = 0; c < HDIM; ++c) h2[c] = fmaf(v, W2[k * HDIM + c], h2[c]);
    }
    #pragma unroll
    for (int c = 0; c < HDIM; ++c) h2[c] = fast_silu(h2[c]);

    float m[COUT];
    #pragma unroll
    for (int c = 0; c < COUT; ++c) m[c] = b3s[c];
    for (int k = 0; k < HDIM; ++k) {
        float v = h2[k];
        #pragma unroll
        for (int c = 0; c < COUT; ++c) m[c] = fmaf(v, W3s[k * COUT + c], m[c]);
    }

    float* op = out + (size_t)row * COUT;
    #pragma unroll
    for (int c = 0; c < COUT; ++c) atomicAdd(op + c, m[c]);
}

extern "C" void kernel_launch(void* const* d_in, const int* in_sizes, int n_in,
                              void* d_out, int out_size, void* d_ws, size_t ws_size,
                              hipStream_t stream) {
    const float* feat = (const float*)d_in[0];
    const float* pos  = (const float*)d_in[1];
    const float* W1   = (const float*)d_in[2];
    const float* b1   = (const float*)d_in[3];
    const float* W2   = (const float*)d_in[4];
    const float* b2   = (const float*)d_in[5];
    const float* W3   = (const float*)d_in[6];
    const float* b3   = (const float*)d_in[7];
    const int*   ei   = (const int*)d_in[8];
    float* outf = (float*)d_out;

    // ws layout
    int* cnt    = (int*)d_ws;             // 50000
    int* off    = cnt + NNODES;           // 50002 (padded even)
    int* cursor = off + NNODES + 2;       // 50000
    const size_t head_ints = ((size_t)NNODES + (NNODES + 2) + NNODES + 3) & ~(size_t)3;
    float* fbase = (float*)(((int*)d_ws) + head_ints);
    float* W3s = fbase;                   // 1024
    float* b3s = W3s + HDIM * COUT;       // 32
    float* prm = b3s + COUT;              // 192
    const size_t head_floats = HDIM * COUT + COUT + 192;  // 1248
    __half* g1h = (__half*)(fbase + head_floats);          // 1.6M halves
    unsigned int* msg = (unsigned int*)(g1h + (size_t)NNODES * HDIM);
    size_t need = (head_ints + head_floats) * 4
                + (size_t)NNODES * HDIM * 2
                + (size_t)NEDGES * 64;

    if (ws_size >= need) {
        (void)hipMemsetAsync(cnt, 0, (size_t)NNODES * sizeof(int), stream);
        nt_hist<<<NT_BLOCKS + HIST_BLOCKS, 256, 0, stream>>>(feat, W1, ei, g1h, cnt, 1);
        scan_all<<<2, 1024, 0, stream>>>(cnt, off, cursor, W3, b3, W1, b1, W3s, b3s, prm);
        edge_compute_g1<<<(NEDGES + 255) / 256, 256, 0, stream>>>(
            g1h, pos, prm, W2, b2, W3s, b3s, ei, cursor, msg);
        gather_kernel<<<(NNODES + 3) / 4, 256, 0, stream>>>(msg, off, outf);
    } else {
        (void)hipMemsetAsync(d_out, 0, (size_t)out_size * sizeof(float), stream);
        prep_w3<<<1, 1024, 0, stream>>>(W3, b3, W1, b1, W3s, b3s, prm);
        edge_atomic_kernel<<<(NEDGES + 255) / 256, 256, 0, stream>>>(
            feat, pos, W1, b1, W2, b2, W3s, b3s, ei, outf);
    }
}

// Round 8
// 153.363 us; speedup vs baseline: 1.6394x; 1.6394x over previous
//
#include <hip/hip_runtime.h>
#include <hip/hip_fp16.h>

#define NNODES 50000
#define NEDGES 800000
#define CIN 64
#define COUT 32
#define NSH 9
#define HDIM 32

#define NT_BLOCKS 6250      // 50000*32/256
#define HIST_BLOCKS 782     // ceil(800000/4/256)
#define SCAN_BLOCKS 125
#define SCAN_CHUNK 400      // 125*400 = 50000 exactly

// ---- shared prep body: collapsed W3/b3 + SH-combined layer-1 params
// prm layout: [b1e(32) | A(32) | B(32) | C(32) | D(32) | E(32)]
__device__ __forceinline__ void prep_body(
    int t, const float* __restrict__ W3, const float* __restrict__ b3,
    const float* __restrict__ W1, const float* __restrict__ b1,
    float* __restrict__ W3s, float* __restrict__ b3s, float* __restrict__ prm)
{
    if (t < HDIM * COUT) {
        int k = t >> 5, c = t & 31;
        float s = 0.f;
        #pragma unroll
        for (int q = 0; q < NSH; ++q) s += W3[k * (NSH * COUT) + q * COUT + c];
        W3s[t] = s;
    }
    if (t < COUT) {
        float s = 0.f;
        #pragma unroll
        for (int q = 0; q < NSH; ++q) s += b3[q * COUT + t];
        b3s[t] = s;
    }
    if (t < HDIM) {
        const float c00 = 0.28209479177387814f;
        const float c1  = 0.3454941494713355f;
        const float c1z = 0.4886025119029199f;
        const float c2  = 0.38627420202318958f;
        const float c2z = 0.7725484040463791f;
        const float c20 = 0.31539156525252005f;
        prm[t]       = b1[t] + c00 * W1[0 * HDIM + t];
        prm[32 + t]  = c1  * (W1[3 * HDIM + t] - W1[1 * HDIM + t]);   // x
        prm[64 + t]  = c1z *  W1[2 * HDIM + t];                       // z
        prm[96 + t]  = c2z * (W1[7 * HDIM + t] - W1[5 * HDIM + t]);   // zx
        prm[128 + t] = c2  * (W1[4 * HDIM + t] + W1[8 * HDIM + t]);   // x^2-y^2
        prm[160 + t] = c20 *  W1[6 * HDIM + t];                       // 2z^2-x^2-y^2
    }
}

__global__ void prep_w3(const float* __restrict__ W3, const float* __restrict__ b3,
                        const float* __restrict__ W1, const float* __restrict__ b1,
                        float* __restrict__ W3s, float* __restrict__ b3s,
                        float* __restrict__ prm) {
    prep_body(threadIdx.x, W3, b3, W1, b1, W3s, b3s, prm);
}

// ---- fused: node transform g1(fp16) = feat @ W1[9:,:]  +  edge-row histogram
__global__ __launch_bounds__(256) void nt_hist(
    const float* __restrict__ feat, const float* __restrict__ W1,
    const int* __restrict__ ei, __half* __restrict__ g1h,
    int* __restrict__ cnt, int do_nt)
{
    int b = blockIdx.x;
    if (do_nt && b < NT_BLOCKS) {
        int tid = b * 256 + threadIdx.x;
        int n = tid >> 5, c = tid & 31;
        if (n < NNODES) {
            float acc = 0.f;
            const float* fr = feat + (size_t)n * CIN;
            const float* wp = W1 + NSH * HDIM + c;
            #pragma unroll 8
            for (int k = 0; k < CIN; ++k)
                acc = fmaf(fr[k], wp[k * HDIM], acc);
            g1h[(size_t)n * HDIM + c] = __float2half(acc);
        }
    } else {
        int hb = do_nt ? (b - NT_BLOCKS) : b;
        int e4 = (hb * 256 + threadIdx.x) * 4;
        if (e4 < NEDGES) {
            int4 r = *reinterpret_cast<const int4*>(ei + e4);
            atomicAdd(&cnt[r.x], 1);
            atomicAdd(&cnt[r.y], 1);
            atomicAdd(&cnt[r.z], 1);
            atomicAdd(&cnt[r.w], 1);
        }
    }
}

// ---- scan phase 1: per-block sums (125 blocks x 400 nodes)
__global__ __launch_bounds__(256) void scan_bsum(const int* __restrict__ cnt,
                                                 int* __restrict__ bsum) {
    int b = blockIdx.x, t = threadIdx.x;
    int base = b * SCAN_CHUNK;
    int s = 0;
    for (int i = t; i < SCAN_CHUNK; i += 256) s += cnt[base + i];
    #pragma unroll
    for (int d = 32; d > 0; d >>= 1) s += __shfl_down(s, d);
    __shared__ int l4[4];
    if ((t & 63) == 0) l4[t >> 6] = s;
    __syncthreads();
    if (t == 0) bsum[b] = l4[0] + l4[1] + l4[2] + l4[3];
}

// ---- scan phase 2 (block 0) + weight prep (block 1), fused
__global__ __launch_bounds__(1024) void scan_top_prep(
    const int* __restrict__ bsum, int* __restrict__ ebsum, int* __restrict__ off,
    const float* __restrict__ W3, const float* __restrict__ b3,
    const float* __restrict__ W1, const float* __restrict__ b1,
    float* __restrict__ W3s, float* __restrict__ b3s, float* __restrict__ prm)
{
    if (blockIdx.x == 1) {
        prep_body(threadIdx.x, W3, b3, W1, b1, W3s, b3s, prm);
        return;
    }
    __shared__ int lds[128];
    int t = threadIdx.x;
    if (t < 128) lds[t] = (t < SCAN_BLOCKS) ? bsum[t] : 0;
    __syncthreads();
    for (int d = 1; d < 128; d <<= 1) {
        int u = (t >= d && t < 128) ? lds[t - d] : 0;
        __syncthreads();
        if (t < 128) lds[t] += u;
        __syncthreads();
    }
    if (t < SCAN_BLOCKS) ebsum[t] = (t == 0) ? 0 : lds[t - 1];
    if (t == 0) off[NNODES] = NEDGES;
}

// ---- scan phase 3: per-block exclusive offsets + cursor init
__global__ __launch_bounds__(256) void scan_offsets(const int* __restrict__ cnt,
                                                    const int* __restrict__ ebsum,
                                                    int* __restrict__ off,
                                                    int* __restrict__ cursor) {
    int b = blockIdx.x, t = threadIdx.x;
    int base = b * SCAN_CHUNK;
    __shared__ int lds[256];
    int2 c2 = make_int2(0, 0);
    if (t < SCAN_CHUNK / 2) c2 = reinterpret_cast<const int2*>(cnt + base)[t];
    int ps = c2.x + c2.y;
    lds[t] = ps;
    __syncthreads();
    for (int d = 1; d < 256; d <<= 1) {
        int u = (t >= d) ? lds[t - d] : 0;
        __syncthreads();
        lds[t] += u;
        __syncthreads();
    }
    int excl = lds[t] - ps;
    if (t < SCAN_CHUNK / 2) {
        int o = ebsum[b] + excl;
        int2 w = make_int2(o, o + c2.x);
        reinterpret_cast<int2*>(off + base)[t] = w;
        reinterpret_cast<int2*>(cursor + base)[t] = w;
    }
}

__device__ __forceinline__ float fast_silu(float v) {
    return v * __builtin_amdgcn_rcpf(1.f + __expf(-v));
}

// ---- main edge kernel: g1(fp16) + SH-combined params, fp16 msg output
__global__ __launch_bounds__(256) void edge_compute_g1(
    const __half* __restrict__ g1h, const float* __restrict__ pos,
    const float* __restrict__ prm,
    const float* __restrict__ W2, const float* __restrict__ b2,
    const float* __restrict__ W3s, const float* __restrict__ b3s,
    const int* __restrict__ ei, int* __restrict__ cursor,
    unsigned int* __restrict__ msg)
{
    int e = blockIdx.x * blockDim.x + threadIdx.x;
    if (e >= NEDGES) return;
    int row = ei[e];
    int col = ei[NEDGES + e];

    // claim slot EARLY: atomic latency hides under the MLP below
    int slot = atomicAdd(&cursor[row], 1);
    unsigned int* mp = msg + (size_t)slot * 16;

    float px = pos[3 * row + 0] - pos[3 * col + 0];
    float py = pos[3 * row + 1] - pos[3 * col + 1];
    float pz = pos[3 * row + 2] - pos[3 * col + 2];
    float r2 = px * px + py * py + pz * pz;
    // guarded rsq: self-loops (r2==0) give x=y=z=0 exactly, matching reference
    float rs = (r2 >= 1e-16f) ? __builtin_amdgcn_rsqf(r2) : 0.f;
    float x = px * rs, y = py * rs, z = pz * rs;

    float zx = z * x;
    float xxyy = x * x - y * y;
    float w6 = 2.f * z * z - x * x - y * y;

    const float* b1e = prm;
    const float* A = prm + 32;
    const float* B = prm + 64;
    const float* C = prm + 96;
    const float* D = prm + 128;
    const float* E = prm + 160;

    // load g1[col] (32 fp16 = 64B) and unpack
    float h1[HDIM];
    const uint4* g4 = reinterpret_cast<const uint4*>(g1h + (size_t)col * HDIM);
    #pragma unroll
    for (int q = 0; q < 4; ++q) {
        uint4 u = g4[q];
        const unsigned int uw[4] = {u.x, u.y, u.z, u.w};
        #pragma unroll
        for (int j = 0; j < 4; ++j) {
            float2 f = __half22float2(*reinterpret_cast<const __half2*>(&uw[j]));
            h1[8 * q + 2 * j]     = f.x;
            h1[8 * q + 2 * j + 1] = f.y;
        }
    }
    #pragma unroll
    for (int c = 0; c < HDIM; ++c) {
        float v = h1[c] + b1e[c];
        v = fmaf(x, A[c], v);
        v = fmaf(z, B[c], v);
        v = fmaf(zx, C[c], v);
        v = fmaf(xxyy, D[c], v);
        v = fmaf(w6, E[c], v);
        h1[c] = fast_silu(v);
    }

    float h2[HDIM];
    #pragma unroll
    for (int c = 0; c < HDIM; ++c) h2[c] = b2[c];
    for (int k = 0; k < HDIM; ++k) {
        float v = h1[k];
        #pragma unroll
        for (int c = 0; c < HDIM; ++c) h2[c] = fmaf(v, W2[k * HDIM + c], h2[c]);
    }
    #pragma unroll
    for (int c = 0; c < HDIM; ++c) h2[c] = fast_silu(h2[c]);

    float m[COUT];
    #pragma unroll
    for (int c = 0; c < COUT; ++c) m[c] = b3s[c];
    for (int k = 0; k < HDIM; ++k) {
        float v = h2[k];
        #pragma unroll
        for (int c = 0; c < COUT; ++c) m[c] = fmaf(v, W3s[k * COUT + c], m[c]);
    }

    // pack to fp16 and store 64B
    uint4 pk[4];
    unsigned int* pu = reinterpret_cast<unsigned int*>(pk);
    #pragma unroll
    for (int q = 0; q < 16; ++q) {
        __half2 hh = __floats2half2_rn(m[2 * q], m[2 * q + 1]);
        pu[q] = *reinterpret_cast<unsigned int*>(&hh);
    }
    uint4* mp4 = reinterpret_cast<uint4*>(mp);
    #pragma unroll
    for (int q = 0; q < 4; ++q) mp4[q] = pk[q];
}

// ---- gather: one wave per node; lane=16g+p; 4 slots (256B) per iter
__global__ __launch_bounds__(256) void gather_kernel(
    const unsigned int* __restrict__ msg, const int* __restrict__ off,
    float* __restrict__ out)
{
    int node = blockIdx.x * 4 + (threadIdx.x >> 6);
    if (node >= NNODES) return;
    int lane = threadIdx.x & 63;
    int g = lane >> 4, p = lane & 15;
    int s0 = off[node], s1 = off[node + 1];
    float ax = 0.f, ay = 0.f;
    for (int s = s0 + g; s < s1; s += 4) {
        unsigned int u = msg[(size_t)s * 16 + p];
        __half2 h = *reinterpret_cast<__half2*>(&u);
        ax += __low2float(h);
        ay += __high2float(h);
    }
    ax += __shfl_xor(ax, 16); ay += __shfl_xor(ay, 16);
    ax += __shfl_xor(ax, 32); ay += __shfl_xor(ay, 32);
    if (lane < 16)
        reinterpret_cast<float2*>(out + (size_t)node * COUT)[p] = make_float2(ax, ay);
}

// ---- fallback: direct fp32 atomic scatter (only if ws too small)
__global__ __launch_bounds__(256) void edge_atomic_kernel(
    const float* __restrict__ feat, const float* __restrict__ pos,
    const float* __restrict__ W1, const float* __restrict__ b1,
    const float* __restrict__ W2, const float* __restrict__ b2,
    const float* __restrict__ W3s, const float* __restrict__ b3s,
    const int* __restrict__ ei, float* __restrict__ out)
{
    int e = blockIdx.x * blockDim.x + threadIdx.x;
    if (e >= NEDGES) return;
    int row = ei[e];
    int col = ei[NEDGES + e];

    float px = pos[3 * row + 0] - pos[3 * col + 0];
    float py = pos[3 * row + 1] - pos[3 * col + 1];
    float pz = pos[3 * row + 2] - pos[3 * col + 2];
    float r2 = px * px + py * py + pz * pz;
    float rs = (r2 >= 1e-16f) ? __builtin_amdgcn_rsqf(r2) : 0.f;
    float x = px * rs, y = py * rs, z = pz * rs;

    const float c00 = 0.28209479177387814f;
    const float c1  = 0.3454941494713355f;
    const float c1z = 0.4886025119029199f;
    const float c2  = 0.38627420202318958f;
    const float c2z = 0.7725484040463791f;
    const float c20 = 0.31539156525252005f;

    float sh[NSH];
    float xxyy = x * x - y * y;
    float zx = z * x;
    sh[0] = c00;
    sh[1] = -c1 * x;
    sh[2] = c1z * z;
    sh[3] = c1 * x;
    sh[4] = c2 * xxyy;
    sh[5] = -c2z * zx;
    sh[6] = c20 * (2.f * z * z - x * x - y * y);
    sh[7] = c2z * zx;
    sh[8] = c2 * xxyy;

    float h1[HDIM];
    #pragma unroll
    for (int c = 0; c < HDIM; ++c) h1[c] = b1[c];
    #pragma unroll
    for (int k = 0; k < NSH; ++k) {
        float v = sh[k];
        #pragma unroll
        for (int c = 0; c < HDIM; ++c) h1[c] = fmaf(v, W1[k * HDIM + c], h1[c]);
    }
    const float4* f4 = reinterpret_cast<const float4*>(feat + (size_t)col * CIN);
    for (int kk = 0; kk < CIN / 4; ++kk) {
        float4 f = f4[kk];
        const float* Wp = W1 + (NSH + kk * 4) * HDIM;
        #pragma unroll
        for (int c = 0; c < HDIM; ++c) h1[c] = fmaf(f.x, Wp[c], h1[c]);
        #pragma unroll
        for (int c = 0; c < HDIM; ++c) h1[c] = fmaf(f.y, Wp[HDIM + c], h1[c]);
        #pragma unroll
        for (int c = 0; c < HDIM; ++c) h1[c] = fmaf(f.z, Wp[2 * HDIM + c], h1[c]);
        #pragma unroll
        for (int c = 0; c < HDIM; ++c) h1[c] = fmaf(f.w, Wp[3 * HDIM + c], h1[c]);
    }
    #pragma unroll
    for (int c = 0; c < HDIM; ++c) h1[c] = fast_silu(h1[c]);

    float h2[HDIM];
    #pragma unroll
    for (int c = 0; c < HDIM; ++c) h2[c] = b2[c];
    for (int k = 0; k < HDIM; ++k) {
        float v = h1[k];
        #pragma unroll
        for (int c = 0; c < HDIM; ++c) h2[c] = fmaf(v, W2[k * HDIM + c], h2[c]);
    }
    #pragma unroll
    for (int c = 0; c < HDIM; ++c) h2[c] = fast_silu(h2[c]);

    float m[COUT];
    #pragma unroll
    for (int c = 0; c < COUT; ++c) m[c] = b3s[c];
    for (int k = 0; k < HDIM; ++k) {
        float v = h2[k];
        #pragma unroll
        for (int c = 0; c < COUT; ++c) m[c] = fmaf(v, W3s[k * COUT + c], m[c]);
    }

    float* op = out + (size_t)row * COUT;
    #pragma unroll
    for (int c = 0; c < COUT; ++c) atomicAdd(op + c, m[c]);
}

extern "C" void kernel_launch(void* const* d_in, const int* in_sizes, int n_in,
                              void* d_out, int out_size, void* d_ws, size_t ws_size,
                              hipStream_t stream) {
    const float* feat = (const float*)d_in[0];
    const float* pos  = (const float*)d_in[1];
    const float* W1   = (const float*)d_in[2];
    const float* b1   = (const float*)d_in[3];
    const float* W2   = (const float*)d_in[4];
    const float* b2   = (const float*)d_in[5];
    const float* W3   = (const float*)d_in[6];
    const float* b3   = (const float*)d_in[7];
    const int*   ei   = (const int*)d_in[8];
    float* outf = (float*)d_out;

    // ws layout
    int* cnt    = (int*)d_ws;             // 50000
    int* off    = cnt + NNODES;           // 50002 (padded even for int2)
    int* cursor = off + NNODES + 2;       // 50000
    int* bsum   = cursor + NNODES;        // 128
    int* ebsum  = bsum + 128;             // 128
    const size_t head_ints = ((size_t)NNODES + (NNODES + 2) + NNODES + 128 + 128 + 3) & ~(size_t)3;
    float* fbase = (float*)(((int*)d_ws) + head_ints);
    float* W3s = fbase;                   // 1024
    float* b3s = W3s + HDIM * COUT;       // 32
    float* prm = b3s + COUT;              // 192
    const size_t head_floats = HDIM * COUT + COUT + 192;  // 1248
    __half* g1h = (__half*)(fbase + head_floats);          // 1.6M halves
    unsigned int* msg = (unsigned int*)(g1h + (size_t)NNODES * HDIM);
    size_t need = (head_ints + head_floats) * 4
                + (size_t)NNODES * HDIM * 2
                + (size_t)NEDGES * 64;

    if (ws_size >= need) {
        (void)hipMemsetAsync(cnt, 0, (size_t)NNODES * sizeof(int), stream);
        nt_hist<<<NT_BLOCKS + HIST_BLOCKS, 256, 0, stream>>>(feat, W1, ei, g1h, cnt, 1);
        scan_bsum<<<SCAN_BLOCKS, 256, 0, stream>>>(cnt, bsum);
        scan_top_prep<<<2, 1024, 0, stream>>>(bsum, ebsum, off, W3, b3, W1, b1, W3s, b3s, prm);
        scan_offsets<<<SCAN_BLOCKS, 256, 0, stream>>>(cnt, ebsum, off, cursor);
        edge_compute_g1<<<(NEDGES + 255) / 256, 256, 0, stream>>>(
            g1h, pos, prm, W2, b2, W3s, b3s, ei, cursor, msg);
        gather_kernel<<<(NNODES + 3) / 4, 256, 0, stream>>>(msg, off, outf);
    } else {
        (void)hipMemsetAsync(d_out, 0, (size_t)out_size * sizeof(float), stream);
        prep_w3<<<1, 1024, 0, stream>>>(W3, b3, W1, b1, W3s, b3s, prm);
        edge_atomic_kernel<<<(NEDGES + 255) / 256, 256, 0, stream>>>(
            feat, pos, W1, b1, W2, b2, W3s, b3s, ei, outf);
    }
}